// Round 9
// baseline (168.675 us; speedup 1.0000x reference)
//
#include <hip/hip_runtime.h>
#include <hip/hip_bf16.h>
#include <cstdint>

// AttentionHead: B=8, S=4096, E=768, H=64. fp32 in/out.
// Reference quirks: v = x@Wq.T (source bug), softmax over QUERY axis,
// scale = 1/sqrt(S) = 1/64.
//
// out[q,h] = sum_k exp(s[q,k]) * v[k,h] / Z[k],  Z[k] = sum_q exp(s[q,k])
// Qb = bf16(q * 0.125*log2e), Kb = bf16(k * 0.125)  =>  dot(Qb,Kb) = log2e*s
// P = exp2(dot) = e^s. VT[h,k] = cv[k]*Qb[k,h], cv = CSCALE/Z[k].
// |s| <= ~1 -> no max subtraction needed.
//
// R9 = R8 with the keepalive compile fix (pass-by-value; vector elements
// cannot bind to float&). Diagnostic ATTN_REPS=3 retained: attn compute
// runs 3x (bitwise-identical output; reps 0-1 kept live via asm) so the
// attn dispatch exceeds the 56us harness fills and surfaces in rocprof.

#define BATCH 8
#define SEQ   4096
#define EMB   768
#define HD    64
#define NROW  (BATCH*SEQ)  // 32768

#define QSCALE 0.1803368801111201f   // 0.125 * log2(e)
#define KSCALE 0.125f
#define CSCALE 5.545177444479562f    // 1 / QSCALE

#define ATTN_REPS 3   // diagnostic multiplier; revert to 1 after profiling

typedef float  f32x4  __attribute__((ext_vector_type(4)));
typedef float  f32x16 __attribute__((ext_vector_type(16)));
typedef __bf16 bf16x8 __attribute__((ext_vector_type(8)));
typedef unsigned short u16x8_t __attribute__((ext_vector_type(8)));
typedef unsigned int   u32x4_t __attribute__((ext_vector_type(4)));

__device__ __forceinline__ f32x4 mfma16(bf16x8 a, bf16x8 b, f32x4 c) {
  return __builtin_amdgcn_mfma_f32_16x16x32_bf16(a, b, c, 0, 0, 0);
}
__device__ __forceinline__ f32x16 mfma32(bf16x8 a, bf16x8 b, f32x16 c) {
  return __builtin_amdgcn_mfma_f32_32x32x16_bf16(a, b, c, 0, 0, 0);
}
__device__ __forceinline__ unsigned short f2b(float f) {
  __bf16 h = (__bf16)f;
  return __builtin_bit_cast(unsigned short, h);
}
__device__ __forceinline__ float b2f(unsigned short u) {
  unsigned int x = ((unsigned int)u) << 16;
  return __builtin_bit_cast(float, x);
}
__device__ __forceinline__ unsigned short f2h(float f) {
  _Float16 h = (_Float16)f;
  return __builtin_bit_cast(unsigned short, h);
}
__device__ __forceinline__ float h2f(unsigned short u) {
  return (float)__builtin_bit_cast(_Float16, u);
}
__device__ __forceinline__ bf16x8 ldsA(const unsigned short* p) {
  return __builtin_bit_cast(bf16x8, *(const u16x8_t*)p);
}
__device__ __forceinline__ bf16x8 ldg8(const unsigned short* p) {
  return __builtin_bit_cast(bf16x8, *(const u16x8_t*)p);
}
__device__ __forceinline__ float expf2(float x) {  // 2^x
  float r; asm("v_exp_f32 %0, %1" : "=v"(r) : "v"(x)); return r;
}
__device__ __forceinline__ unsigned cvtpk(float lo, float hi) {  // 2 f32 -> 2 bf16
  unsigned r; asm("v_cvt_pk_bf16_f32 %0, %1, %2" : "=v"(r) : "v"(lo), "v"(hi)); return r;
}
__device__ __forceinline__ void plane32swap(unsigned &a, unsigned &b) {
  asm volatile("v_permlane32_swap_b32 %0, %1" : "+v"(a), "+v"(b));
}
__device__ __forceinline__ void glld16(const void* g, void* l) {
  __builtin_amdgcn_global_load_lds(
      (const __attribute__((address_space(1))) void*)g,
      (__attribute__((address_space(3))) void*)l, 16, 0, 0);
}
__device__ __forceinline__ float keepalive(float x) {  // anti-DCE (rule 17)
  asm volatile("" : "+v"(x));
  return x;
}
// G4 XOR swizzle for row-major [R][64] bf16 tiles (halfword index)
__device__ __forceinline__ int sidx(int r, int h) {
  return r * 64 + (h ^ ((r & 7) << 3));
}

// ---------------- Kernel 0: W -> bf16 (Wq rows 0-63 | Wk rows 64-127) ----
__global__ __launch_bounds__(256) void wcvt_kernel(
    const float* __restrict__ Wq, const float* __restrict__ Wk,
    unsigned short* __restrict__ Wb) {
  int ci = blockIdx.x * 256 + threadIdx.x;  // 12288 chunks of 8
  int r = ci / 96, c8 = ci % 96;
  const float* src = (r < 64 ? Wq + (size_t)r * EMB : Wk + (size_t)(r - 64) * EMB) + c8 * 8;
  float4 a = *(const float4*)src, d = *(const float4*)(src + 4);
  u16x8_t o;
  o[0]=f2b(a.x); o[1]=f2b(a.y); o[2]=f2b(a.z); o[3]=f2b(a.w);
  o[4]=f2b(d.x); o[5]=f2b(d.y); o[6]=f2b(d.z); o[7]=f2b(d.w);
  *(u16x8_t*)(Wb + (size_t)ci * 8) = o;
}

// ---------------- Kernel 1: projection GEMM (+X register prefetch) -------
// Qb = bf16(X@Wq.T * QSCALE), Kb = bf16(X@Wk.T * KSCALE). M-tile 64, 512
// blocks. X loads for chunk ec+1 issue BEFORE compute of chunk ec (T14) so
// HBM latency hides under the 16-MFMA compute phase.
__global__ __launch_bounds__(256) void proj_kernel(
    const float* __restrict__ X, const unsigned short* __restrict__ Wb,
    unsigned short* __restrict__ Qb, unsigned short* __restrict__ Kb) {
  __shared__ unsigned short Ws[2][8192];
  const int t = threadIdx.x, lane = t & 63, w = t >> 6;
  const int c = lane & 15, g = lane >> 4;
  const int row0 = blockIdx.x * 64;
  f32x4 acc[8];
#pragma unroll
  for (int f = 0; f < 8; ++f) { acc[f][0]=0.f; acc[f][1]=0.f; acc[f][2]=0.f; acc[f][3]=0.f; }

  auto STAGE = [&](int ec, int bb) {
#pragma unroll
    for (int i = 0; i < 4; ++i) {
      int rr = w + 4 * i;               // uniform per wave
      int ci = rr * 64 + lane;
      int r = ci >> 3, cL = ci & 7;
      glld16(Wb + (size_t)r * EMB + ec * 64 + (cL ^ (r & 7)) * 8, (void*)&Ws[bb][rr * 512]);
    }
  };
  const float* xrow = X + (size_t)(row0 + 16 * w + c) * EMB + 8 * g;
  float4 Xa[4], Xb[4];
  auto LOADX = [&](float4* R, int ec) {
    const float* xp = xrow + ec * 64;
    R[0] = *(const float4*)xp;        R[1] = *(const float4*)(xp + 4);
    R[2] = *(const float4*)(xp + 32); R[3] = *(const float4*)(xp + 36);
  };
  auto COMPUTE = [&](const float4* R, const unsigned short* Wt) {
    bf16x8 Af[2];
#pragma unroll
    for (int es = 0; es < 2; ++es) {
      float4 v0 = R[2 * es], v1 = R[2 * es + 1];
      u16x8_t tmp;
      tmp[0]=f2b(v0.x); tmp[1]=f2b(v0.y); tmp[2]=f2b(v0.z); tmp[3]=f2b(v0.w);
      tmp[4]=f2b(v1.x); tmp[5]=f2b(v1.y); tmp[6]=f2b(v1.z); tmp[7]=f2b(v1.w);
      Af[es] = __builtin_bit_cast(bf16x8, tmp);
    }
#pragma unroll
    for (int es = 0; es < 2; ++es)
#pragma unroll
      for (int f = 0; f < 8; ++f) {
        bf16x8 Bf = ldsA(&Wt[sidx(16 * f + c, es * 32 + 8 * g)]);
        acc[f] = mfma16(Af[es], Bf, acc[f]);
      }
  };

  LOADX(Xa, 0);
  STAGE(0, 0);
  __syncthreads();
#pragma unroll 1
  for (int e2 = 0; e2 < 6; ++e2) {
    int ec = 2 * e2;
    if (ec + 1 < 12) { STAGE(ec + 1, (ec + 1) & 1); LOADX(Xb, ec + 1); }
    COMPUTE(Xa, Ws[ec & 1]);
    __syncthreads();
    if (ec + 2 < 12) { STAGE(ec + 2, (ec + 2) & 1); LOADX(Xa, ec + 2); }
    COMPUTE(Xb, Ws[(ec + 1) & 1]);
    __syncthreads();
  }
#pragma unroll
  for (int f = 0; f < 8; ++f) {
    int n = 16 * f + c;
    float sc = (n < 64) ? QSCALE : KSCALE;
#pragma unroll
    for (int r = 0; r < 4; ++r) {
      int ROW = row0 + 16 * w + 4 * g + r;
      unsigned short bv = f2b(acc[f][r] * sc);
      if (n < 64) Qb[(size_t)ROW * 64 + n] = bv;
      else        Kb[(size_t)ROW * 64 + (n - 64)] = bv;
    }
  }
}

// ---------------- Kernel 2: column exp2-sums (R6-verbatim) ----------------
__global__ __launch_bounds__(256) void colsum_kernel(
    const unsigned short* __restrict__ Qb, const unsigned short* __restrict__ Kb,
    float* __restrict__ Zpart) {
  __shared__ unsigned short Qs[2][8192];
  const int t = threadIdx.x, lane = t & 63, w = t >> 6;
  const int c = lane & 31, hi = lane >> 5;
  const int fid = blockIdx.x;
  const int b = fid & 7, rem = fid >> 3;
  const int kt = rem & 15, qs = rem >> 4;
  const size_t kbase = (size_t)b * SEQ + kt * 256;
  const size_t qbase0 = (size_t)b * SEQ + qs * 1024;

  bf16x8 Kf[2][4];  // own 64 k-rows: kbase + 64w + 32j + c
#pragma unroll
  for (int j = 0; j < 2; ++j)
#pragma unroll
    for (int es = 0; es < 4; ++es)
      Kf[j][es] = __builtin_bit_cast(bf16x8,
          *(const u16x8_t*)(Kb + (kbase + 64 * w + 32 * j + c) * 64 + 16 * es + 8 * hi));

  auto STAGE = [&](int qi, int bb) {
#pragma unroll
    for (int i = 0; i < 4; ++i) {
      int rr = w + 4 * i;
      int ci = rr * 64 + lane;
      int r = ci >> 3, cL = ci & 7;
      glld16(Qb + (qbase0 + qi * 128 + r) * 64 + (cL ^ (r & 7)) * 8, (void*)&Qs[bb][rr * 512]);
    }
  };
  float csum[2] = {0.f, 0.f};
  STAGE(0, 0);
  __syncthreads();
  for (int qi = 0; qi < 8; ++qi) {
    if (qi < 7) STAGE(qi + 1, (qi + 1) & 1);
    const unsigned short* Qt = Qs[qi & 1];
#pragma unroll
    for (int sq = 0; sq < 4; ++sq) {
      bf16x8 A[4];
#pragma unroll
      for (int es = 0; es < 4; ++es)
        A[es] = ldsA(&Qt[sidx(32 * sq + c, 16 * es + 8 * hi)]);
#pragma unroll
      for (int j = 0; j < 2; ++j) {
        f32x16 sv;
#pragma unroll
        for (int i = 0; i < 16; ++i) sv[i] = 0.f;
#pragma unroll
        for (int es = 0; es < 4; ++es) sv = mfma32(A[es], Kf[j][es], sv);
#pragma unroll
        for (int i = 0; i < 16; ++i) csum[j] += expf2(sv[i]);
      }
    }
    __syncthreads();
  }
#pragma unroll
  for (int j = 0; j < 2; ++j) {
    float v = csum[j] + __shfl_xor(csum[j], 32);  // merge hi row-halves
    if (lane < 32)
      Zpart[(kbase + 64 * w + 32 * j + lane) * 4 + qs] = v;
  }
}

// ---------------- Kernel 3: VT[b][h][k] = cv[k]*Qb[k][h] (R6-verbatim) ---
__global__ __launch_bounds__(256) void vtrans_kernel(
    const unsigned short* __restrict__ Qb, const float* __restrict__ Zpart,
    unsigned short* __restrict__ VT) {
  __shared__ unsigned short T[128 * 72];
  __shared__ float cvs[128];
  const int t = threadIdx.x;
  const int kt = blockIdx.x, b = blockIdx.y;
  const size_t kbase = (size_t)b * SEQ + kt * 128;
#pragma unroll
  for (int it = 0; it < 4; ++it) {  // stage 128x64 tile, chunk-swizzled by r>>3
    int ci = t + 256 * it;
    int r = ci >> 3, ch = ci & 7;
    u16x8_t v = *(const u16x8_t*)(Qb + (kbase + r) * 64 + 8 * ch);
    *(u16x8_t*)(&T[r * 72 + 8 * (ch ^ ((r >> 3) & 7))]) = v;
  }
  if (t < 128) {
    const float* zp = Zpart + (kbase + t) * 4;
    cvs[t] = CSCALE / (zp[0] + zp[1] + zp[2] + zp[3]);
  }
  __syncthreads();
#pragma unroll
  for (int it = 0; it < 4; ++it) {
    int ci = t + 256 * it;
    int h = ci >> 4, c16 = ci & 15;
    u16x8_t o;
#pragma unroll
    for (int j = 0; j < 8; ++j) {
      int r = 8 * c16 + j;
      unsigned short raw = T[r * 72 + 8 * ((h >> 3) ^ (c16 & 7)) + (h & 7)];
      o[j] = f2b(cvs[r] * b2f(raw));
    }
    *(u16x8_t*)(VT + ((size_t)(b * 64 + h)) * SEQ + kt * 128 + 8 * c16) = o;
  }
}

// ---------------- Kernel 4: attention (R6 structure, REPS diagnostic) ----
// 256 thr (4 waves), 64 q/wave (2 q-blocks) -> 256 q/block. K+V staged in
// LDS via glld16 (dbuf 2 x (K 4096|V 4096) hw = 32KB). k swept in 64-tiles.
// ATTN_REPS repeats of the full compute (acc re-zeroed; reps <last kept
// live via asm keepalive) -- output bitwise identical to REPS=1.
template <bool F16P>
__global__ __launch_bounds__(256) void attn_kernel(
    const unsigned short* __restrict__ Qb, const unsigned short* __restrict__ Kb,
    const unsigned short* __restrict__ VT, void* __restrict__ outp, int nkt) {
  __shared__ unsigned short KV[2][8192];  // [buf][K 4096 | V 4096] halfwords
  const int t = threadIdx.x, lane = t & 63, w = t >> 6;
  const int c = lane & 31, hi = lane >> 5;
  const int fid = blockIdx.x;
  const int b = fid & 7, rem = fid >> 3;
  const int qt = rem & 15, ks = rem >> 4;
  const size_t brow = (size_t)b * SEQ;
  const int q0 = qt * 256;
  const int ntiles = 2 * nkt;            // 64-wide tiles
  const int t0 = ks * ntiles;            // first tile index

  bf16x8 Qf[2][4];  // persistent B-frags: n = own q row (2 q-blocks of 32)
#pragma unroll
  for (int j = 0; j < 2; ++j)
#pragma unroll
    for (int es = 0; es < 4; ++es)
      Qf[j][es] = ldg8(Qb + (brow + q0 + 64 * w + 32 * j + c) * 64 + 16 * es + 8 * hi);

  f32x16 acc[2][2];

  auto STAGE = [&](int tt, int bb) {
    const int k0 = (t0 + tt) * 64;
    const size_t kb0 = brow + k0;
#pragma unroll
    for (int i = 0; i < 4; ++i) {
      int rr = w + 4 * i;  // uniform per wave; rr<8: K, else V
      if (rr < 8) {
        int ci = rr * 64 + lane;
        int r = ci >> 3, cL = ci & 7;
        glld16(Kb + (kb0 + r) * 64 + (cL ^ (r & 7)) * 8, (void*)&KV[bb][rr * 512]);
      } else {
        int ci = (rr - 8) * 64 + lane;
        int h = ci >> 3, cL = ci & 7;
        glld16(VT + ((size_t)(b * 64 + h)) * SEQ + k0 + (cL ^ (h & 7)) * 8,
               (void*)&KV[bb][4096 + (rr - 8) * 512]);
      }
    }
  };

  auto COMPUTE = [&](int bb) {
    const unsigned short* Ks = &KV[bb][0];
    const unsigned short* Vs = &KV[bb][4096];
#pragma unroll
    for (int kb = 0; kb < 2; ++kb) {
      bf16x8 KA[4];
#pragma unroll
      for (int es = 0; es < 4; ++es)
        KA[es] = ldsA(&Ks[sidx(32 * kb + c, 16 * es + 8 * hi)]);
      bf16x8 fA[2][2];
#pragma unroll
      for (int j = 0; j < 2; ++j) {
        // QK^T swapped: D[k-row][q-col], col = own q
        f32x16 sv;
#pragma unroll
        for (int i = 0; i < 16; ++i) sv[i] = 0.f;
#pragma unroll
        for (int es = 0; es < 4; ++es) sv = mfma32(KA[es], Qf[j][es], sv);
        float p[16];
#pragma unroll
        for (int i = 0; i < 16; ++i) p[i] = expf2(sv[i]);
        unsigned X0 = cvtpk(p[0], p[1]),  X1 = cvtpk(p[2], p[3]);
        unsigned Y0 = cvtpk(p[4], p[5]),  Y1 = cvtpk(p[6], p[7]);
        plane32swap(X0, Y0); plane32swap(X1, Y1);
        u32x4_t F0 = {X0, X1, Y0, Y1};
        unsigned Z0 = cvtpk(p[8], p[9]),   Z1 = cvtpk(p[10], p[11]);
        unsigned W0 = cvtpk(p[12], p[13]), W1 = cvtpk(p[14], p[15]);
        plane32swap(Z0, W0); plane32swap(Z1, W1);
        u32x4_t F1 = {Z0, Z1, W0, W1};
        fA[j][0] = __builtin_bit_cast(bf16x8, F0);
        fA[j][1] = __builtin_bit_cast(bf16x8, F1);
      }
      // PV: acc[j][q][h] += P_j * V'; V-frags shared across j
#pragma unroll
      for (int hb = 0; hb < 2; ++hb) {
        int h = 32 * hb + c;
        int col0 = 32 * kb + 8 * hi;
        bf16x8 VB0 = ldsA(&Vs[h * 64 + (col0 ^ ((h & 7) << 3))]);
        bf16x8 VB1 = ldsA(&Vs[h * 64 + ((col0 + 16) ^ ((h & 7) << 3))]);
        acc[0][hb] = mfma32(fA[0][0], VB0, acc[0][hb]);
        acc[0][hb] = mfma32(fA[0][1], VB1, acc[0][hb]);
        acc[1][hb] = mfma32(fA[1][0], VB0, acc[1][hb]);
        acc[1][hb] = mfma32(fA[1][1], VB1, acc[1][hb]);
      }
    }
  };

#pragma unroll 1
  for (int rep = 0; rep < ATTN_REPS; ++rep) {
#pragma unroll
    for (int j = 0; j < 2; ++j)
#pragma unroll
      for (int hb = 0; hb < 2; ++hb)
#pragma unroll
        for (int i = 0; i < 16; ++i) acc[j][hb][i] = 0.f;
    STAGE(0, 0);
    __syncthreads();
    for (int tt = 0; tt < ntiles; ++tt) {
      if (tt + 1 < ntiles) STAGE(tt + 1, (tt + 1) & 1);
      COMPUTE(tt & 1);
      __syncthreads();
    }
    if (rep < ATTN_REPS - 1) {  // anti-DCE: keep this rep's results live
#pragma unroll
      for (int j = 0; j < 2; ++j)
#pragma unroll
        for (int hb = 0; hb < 2; ++hb)
#pragma unroll
          for (int i = 0; i < 16; ++i) acc[j][hb][i] = keepalive(acc[j][hb][i]);
    }
  }
#pragma unroll
  for (int j = 0; j < 2; ++j)
#pragma unroll
    for (int hb = 0; hb < 2; ++hb)
#pragma unroll
      for (int r = 0; r < 16; ++r) {
        int qrow = (r & 3) + 8 * (r >> 2) + 4 * hi;
        size_t idx = (brow + q0 + 64 * w + 32 * j + qrow) * 64 + 32 * hb + c;
        if (F16P) {
          unsigned short* op = (unsigned short*)outp + (size_t)ks * NROW * 64;
          op[idx] = f2h(acc[j][hb][r]);
        } else {
          ((float*)outp)[idx] = acc[j][hb][r];
        }
      }
}

// ---------------- Kernel 5: combine 4 f16 k-split partials ----------------
__global__ __launch_bounds__(256) void osum_kernel(
    const unsigned short* __restrict__ P, float* __restrict__ O) {
  const size_t PS = (size_t)NROW * 64;
  size_t i = ((size_t)blockIdx.x * 256 + threadIdx.x) * 8;
  u16x8_t a = *(const u16x8_t*)(P + i);
  u16x8_t b = *(const u16x8_t*)(P + PS + i);
  u16x8_t c = *(const u16x8_t*)(P + 2 * PS + i);
  u16x8_t d = *(const u16x8_t*)(P + 3 * PS + i);
  float o[8];
#pragma unroll
  for (int j = 0; j < 8; ++j)
    o[j] = (h2f(a[j]) + h2f(b[j])) + (h2f(c[j]) + h2f(d[j]));
  float4 o0 = {o[0], o[1], o[2], o[3]}, o1 = {o[4], o[5], o[6], o[7]};
  *(float4*)(O + i) = o0;
  *(float4*)(O + i + 4) = o1;
}

extern "C" void kernel_launch(void* const* d_in, const int* in_sizes, int n_in,
                              void* d_out, int out_size, void* d_ws, size_t ws_size,
                              hipStream_t stream) {
  const float* X  = (const float*)d_in[0];
  const float* Wq = (const float*)d_in[1];
  const float* Wk = (const float*)d_in[2];
  // d_in[3] (Wv) unused: reference computes v with q_net.
  float* Out = (float*)d_out;

  unsigned char* wsb = (unsigned char*)d_ws;
  const size_t QB_OFF = 0;                    // 4 MB bf16
  const size_t KB_OFF = 4194304;              // 4 MB bf16
  const size_t WB_OFF = 8388608;              // 192 KB bf16
  const size_t Z_OFF  = 8585216;              // 512 KB f32
  const size_t VT_OFF = 9240576;              // 4 MB bf16
  const size_t OP_OFF = 13434880;             // 16 MB f16 (4 partials)
  const size_t TOTAL_SPLIT = OP_OFF + (size_t)4 * NROW * 64 * 2;

  unsigned short* Qb = (unsigned short*)(wsb + QB_OFF);
  unsigned short* Kb = (unsigned short*)(wsb + KB_OFF);
  unsigned short* Wb = (unsigned short*)(wsb + WB_OFF);
  float* Zpart       = (float*)(wsb + Z_OFF);
  unsigned short* VT = (unsigned short*)(wsb + VT_OFF);
  unsigned short* OpH = (unsigned short*)(wsb + OP_OFF);

  const bool split = (ws_size >= TOTAL_SPLIT);

  hipLaunchKernelGGL(wcvt_kernel, dim3(48), dim3(256), 0, stream, Wq, Wk, Wb);
  hipLaunchKernelGGL(proj_kernel, dim3(NROW / 64), dim3(256), 0, stream, X, Wb, Qb, Kb);
  hipLaunchKernelGGL(colsum_kernel, dim3(512), dim3(256), 0, stream, Qb, Kb, Zpart);
  hipLaunchKernelGGL(vtrans_kernel, dim3(32, 8), dim3(256), 0, stream, Qb, Zpart, VT);
  if (split) {
    hipLaunchKernelGGL(attn_kernel<true>, dim3(512), dim3(256), 0, stream,
                       Qb, Kb, VT, (void*)OpH, 8);
    hipLaunchKernelGGL(osum_kernel, dim3(1024), dim3(256), 0, stream, OpH, Out);
  } else {
    hipLaunchKernelGGL(attn_kernel<false>, dim3(128), dim3(256), 0, stream,
                       Qb, Kb, VT, (void*)Out, 32);
  }
}

// Round 10
// 105.823 us; speedup vs baseline: 1.5939x; 1.5939x over previous
//
#include <hip/hip_runtime.h>
#include <hip/hip_bf16.h>
#include <cstdint>

// AttentionHead: B=8, S=4096, E=768, H=64. fp32 in/out.
// Reference quirks: v = x@Wq.T (source bug), softmax over QUERY axis,
// scale = 1/sqrt(S) = 1/64.
//
// out[q,h] = sum_k exp(s[q,k]) * v[k,h] / Z[k],  Z[k] = sum_q exp(s[q,k])
// Qb = bf16(q * 0.125*log2e), Kb = bf16(k * 0.125)  =>  dot(Qb,Kb) = log2e*s
// P = exp2(dot) = e^s. VT[h,k] = cv[k]*Qb[k,h], cv = CSCALE/Z[k].
// |s| <= ~1 -> no max subtraction needed.
//
// R10: occupancy fix from R9 profile (attn was 2 blocks/CU, 18.5% occ,
// no pipe >55%): attn k-split 4->8 and colsum q-split 4->8 (both grids
// 512->1024 = 4 blocks/CU). osum combines 8 f16 partials. Zpart aliases
// the partial region (dead after vtrans) to hold the proven ws footprint.
// proj keeps the R9 X-register-prefetch (T14, ~16us win).

#define BATCH 8
#define SEQ   4096
#define EMB   768
#define HD    64
#define NROW  (BATCH*SEQ)  // 32768

#define QSCALE 0.1803368801111201f   // 0.125 * log2(e)
#define KSCALE 0.125f
#define CSCALE 5.545177444479562f    // 1 / QSCALE

typedef float  f32x4  __attribute__((ext_vector_type(4)));
typedef float  f32x16 __attribute__((ext_vector_type(16)));
typedef __bf16 bf16x8 __attribute__((ext_vector_type(8)));
typedef unsigned short u16x8_t __attribute__((ext_vector_type(8)));
typedef unsigned int   u32x4_t __attribute__((ext_vector_type(4)));

__device__ __forceinline__ f32x4 mfma16(bf16x8 a, bf16x8 b, f32x4 c) {
  return __builtin_amdgcn_mfma_f32_16x16x32_bf16(a, b, c, 0, 0, 0);
}
__device__ __forceinline__ f32x16 mfma32(bf16x8 a, bf16x8 b, f32x16 c) {
  return __builtin_amdgcn_mfma_f32_32x32x16_bf16(a, b, c, 0, 0, 0);
}
__device__ __forceinline__ unsigned short f2b(float f) {
  __bf16 h = (__bf16)f;
  return __builtin_bit_cast(unsigned short, h);
}
__device__ __forceinline__ float b2f(unsigned short u) {
  unsigned int x = ((unsigned int)u) << 16;
  return __builtin_bit_cast(float, x);
}
__device__ __forceinline__ unsigned short f2h(float f) {
  _Float16 h = (_Float16)f;
  return __builtin_bit_cast(unsigned short, h);
}
__device__ __forceinline__ float h2f(unsigned short u) {
  return (float)__builtin_bit_cast(_Float16, u);
}
__device__ __forceinline__ bf16x8 ldsA(const unsigned short* p) {
  return __builtin_bit_cast(bf16x8, *(const u16x8_t*)p);
}
__device__ __forceinline__ bf16x8 ldg8(const unsigned short* p) {
  return __builtin_bit_cast(bf16x8, *(const u16x8_t*)p);
}
__device__ __forceinline__ float expf2(float x) {  // 2^x
  float r; asm("v_exp_f32 %0, %1" : "=v"(r) : "v"(x)); return r;
}
__device__ __forceinline__ unsigned cvtpk(float lo, float hi) {  // 2 f32 -> 2 bf16
  unsigned r; asm("v_cvt_pk_bf16_f32 %0, %1, %2" : "=v"(r) : "v"(lo), "v"(hi)); return r;
}
__device__ __forceinline__ void plane32swap(unsigned &a, unsigned &b) {
  asm volatile("v_permlane32_swap_b32 %0, %1" : "+v"(a), "+v"(b));
}
__device__ __forceinline__ void glld16(const void* g, void* l) {
  __builtin_amdgcn_global_load_lds(
      (const __attribute__((address_space(1))) void*)g,
      (__attribute__((address_space(3))) void*)l, 16, 0, 0);
}
// G4 XOR swizzle for row-major [R][64] bf16 tiles (halfword index)
__device__ __forceinline__ int sidx(int r, int h) {
  return r * 64 + (h ^ ((r & 7) << 3));
}

// ---------------- Kernel 0: W -> bf16 (Wq rows 0-63 | Wk rows 64-127) ----
__global__ __launch_bounds__(256) void wcvt_kernel(
    const float* __restrict__ Wq, const float* __restrict__ Wk,
    unsigned short* __restrict__ Wb) {
  int ci = blockIdx.x * 256 + threadIdx.x;  // 12288 chunks of 8
  int r = ci / 96, c8 = ci % 96;
  const float* src = (r < 64 ? Wq + (size_t)r * EMB : Wk + (size_t)(r - 64) * EMB) + c8 * 8;
  float4 a = *(const float4*)src, d = *(const float4*)(src + 4);
  u16x8_t o;
  o[0]=f2b(a.x); o[1]=f2b(a.y); o[2]=f2b(a.z); o[3]=f2b(a.w);
  o[4]=f2b(d.x); o[5]=f2b(d.y); o[6]=f2b(d.z); o[7]=f2b(d.w);
  *(u16x8_t*)(Wb + (size_t)ci * 8) = o;
}

// ---------------- Kernel 1: projection GEMM (+X register prefetch, T14) --
__global__ __launch_bounds__(256) void proj_kernel(
    const float* __restrict__ X, const unsigned short* __restrict__ Wb,
    unsigned short* __restrict__ Qb, unsigned short* __restrict__ Kb) {
  __shared__ unsigned short Ws[2][8192];
  const int t = threadIdx.x, lane = t & 63, w = t >> 6;
  const int c = lane & 15, g = lane >> 4;
  const int row0 = blockIdx.x * 64;
  f32x4 acc[8];
#pragma unroll
  for (int f = 0; f < 8; ++f) { acc[f][0]=0.f; acc[f][1]=0.f; acc[f][2]=0.f; acc[f][3]=0.f; }

  auto STAGE = [&](int ec, int bb) {
#pragma unroll
    for (int i = 0; i < 4; ++i) {
      int rr = w + 4 * i;               // uniform per wave
      int ci = rr * 64 + lane;
      int r = ci >> 3, cL = ci & 7;
      glld16(Wb + (size_t)r * EMB + ec * 64 + (cL ^ (r & 7)) * 8, (void*)&Ws[bb][rr * 512]);
    }
  };
  const float* xrow = X + (size_t)(row0 + 16 * w + c) * EMB + 8 * g;
  float4 Xa[4], Xb[4];
  auto LOADX = [&](float4* R, int ec) {
    const float* xp = xrow + ec * 64;
    R[0] = *(const float4*)xp;        R[1] = *(const float4*)(xp + 4);
    R[2] = *(const float4*)(xp + 32); R[3] = *(const float4*)(xp + 36);
  };
  auto COMPUTE = [&](const float4* R, const unsigned short* Wt) {
    bf16x8 Af[2];
#pragma unroll
    for (int es = 0; es < 2; ++es) {
      float4 v0 = R[2 * es], v1 = R[2 * es + 1];
      u16x8_t tmp;
      tmp[0]=f2b(v0.x); tmp[1]=f2b(v0.y); tmp[2]=f2b(v0.z); tmp[3]=f2b(v0.w);
      tmp[4]=f2b(v1.x); tmp[5]=f2b(v1.y); tmp[6]=f2b(v1.z); tmp[7]=f2b(v1.w);
      Af[es] = __builtin_bit_cast(bf16x8, tmp);
    }
#pragma unroll
    for (int es = 0; es < 2; ++es)
#pragma unroll
      for (int f = 0; f < 8; ++f) {
        bf16x8 Bf = ldsA(&Wt[sidx(16 * f + c, es * 32 + 8 * g)]);
        acc[f] = mfma16(Af[es], Bf, acc[f]);
      }
  };

  LOADX(Xa, 0);
  STAGE(0, 0);
  __syncthreads();
#pragma unroll 1
  for (int e2 = 0; e2 < 6; ++e2) {
    int ec = 2 * e2;
    if (ec + 1 < 12) { STAGE(ec + 1, (ec + 1) & 1); LOADX(Xb, ec + 1); }
    COMPUTE(Xa, Ws[ec & 1]);
    __syncthreads();
    if (ec + 2 < 12) { STAGE(ec + 2, (ec + 2) & 1); LOADX(Xa, ec + 2); }
    COMPUTE(Xb, Ws[(ec + 1) & 1]);
    __syncthreads();
  }
#pragma unroll
  for (int f = 0; f < 8; ++f) {
    int n = 16 * f + c;
    float sc = (n < 64) ? QSCALE : KSCALE;
#pragma unroll
    for (int r = 0; r < 4; ++r) {
      int ROW = row0 + 16 * w + 4 * g + r;
      unsigned short bv = f2b(acc[f][r] * sc);
      if (n < 64) Qb[(size_t)ROW * 64 + n] = bv;
      else        Kb[(size_t)ROW * 64 + (n - 64)] = bv;
    }
  }
}

// ---------------- Kernel 2: column exp2-sums (q-split 8) ------------------
// 64 k/wave (2 k-blocks), K-frags persistent; Q staged LDS dbuf. grid 1024
// = 8b x 16kt x 8qs (b = fid&7) -> 4 blocks/CU.
__global__ __launch_bounds__(256) void colsum_kernel(
    const unsigned short* __restrict__ Qb, const unsigned short* __restrict__ Kb,
    float* __restrict__ Zpart) {
  __shared__ unsigned short Qs[2][8192];
  const int t = threadIdx.x, lane = t & 63, w = t >> 6;
  const int c = lane & 31, hi = lane >> 5;
  const int fid = blockIdx.x;
  const int b = fid & 7, rem = fid >> 3;
  const int kt = rem & 15, qs = rem >> 4;      // qs 0..7
  const size_t kbase = (size_t)b * SEQ + kt * 256;
  const size_t qbase0 = (size_t)b * SEQ + qs * 512;

  bf16x8 Kf[2][4];  // own 64 k-rows: kbase + 64w + 32j + c
#pragma unroll
  for (int j = 0; j < 2; ++j)
#pragma unroll
    for (int es = 0; es < 4; ++es)
      Kf[j][es] = __builtin_bit_cast(bf16x8,
          *(const u16x8_t*)(Kb + (kbase + 64 * w + 32 * j + c) * 64 + 16 * es + 8 * hi));

  auto STAGE = [&](int qi, int bb) {
#pragma unroll
    for (int i = 0; i < 4; ++i) {
      int rr = w + 4 * i;
      int ci = rr * 64 + lane;
      int r = ci >> 3, cL = ci & 7;
      glld16(Qb + (qbase0 + qi * 128 + r) * 64 + (cL ^ (r & 7)) * 8, (void*)&Qs[bb][rr * 512]);
    }
  };
  float csum[2] = {0.f, 0.f};
  STAGE(0, 0);
  __syncthreads();
  for (int qi = 0; qi < 4; ++qi) {   // 512 q per block
    if (qi < 3) STAGE(qi + 1, (qi + 1) & 1);
    const unsigned short* Qt = Qs[qi & 1];
#pragma unroll
    for (int sq = 0; sq < 4; ++sq) {
      bf16x8 A[4];
#pragma unroll
      for (int es = 0; es < 4; ++es)
        A[es] = ldsA(&Qt[sidx(32 * sq + c, 16 * es + 8 * hi)]);
#pragma unroll
      for (int j = 0; j < 2; ++j) {
        f32x16 sv;
#pragma unroll
        for (int i = 0; i < 16; ++i) sv[i] = 0.f;
#pragma unroll
        for (int es = 0; es < 4; ++es) sv = mfma32(A[es], Kf[j][es], sv);
#pragma unroll
        for (int i = 0; i < 16; ++i) csum[j] += expf2(sv[i]);
      }
    }
    __syncthreads();
  }
#pragma unroll
  for (int j = 0; j < 2; ++j) {
    float v = csum[j] + __shfl_xor(csum[j], 32);  // merge hi row-halves
    if (lane < 32)
      Zpart[(kbase + 64 * w + 32 * j + lane) * 8 + qs] = v;
  }
}

// ---------------- Kernel 3: VT[b][h][k] = cv[k]*Qb[k][h] ------------------
__global__ __launch_bounds__(256) void vtrans_kernel(
    const unsigned short* __restrict__ Qb, const float* __restrict__ Zpart,
    unsigned short* __restrict__ VT) {
  __shared__ unsigned short T[128 * 72];
  __shared__ float cvs[128];
  const int t = threadIdx.x;
  const int kt = blockIdx.x, b = blockIdx.y;
  const size_t kbase = (size_t)b * SEQ + kt * 128;
#pragma unroll
  for (int it = 0; it < 4; ++it) {  // stage 128x64 tile, chunk-swizzled by r>>3
    int ci = t + 256 * it;
    int r = ci >> 3, ch = ci & 7;
    u16x8_t v = *(const u16x8_t*)(Qb + (kbase + r) * 64 + 8 * ch);
    *(u16x8_t*)(&T[r * 72 + 8 * (ch ^ ((r >> 3) & 7))]) = v;
  }
  if (t < 128) {
    const float* zp = Zpart + (kbase + t) * 8;
    float z = ((zp[0] + zp[1]) + (zp[2] + zp[3])) + ((zp[4] + zp[5]) + (zp[6] + zp[7]));
    cvs[t] = CSCALE / z;
  }
  __syncthreads();
#pragma unroll
  for (int it = 0; it < 4; ++it) {
    int ci = t + 256 * it;
    int h = ci >> 4, c16 = ci & 15;
    u16x8_t o;
#pragma unroll
    for (int j = 0; j < 8; ++j) {
      int r = 8 * c16 + j;
      unsigned short raw = T[r * 72 + 8 * ((h >> 3) ^ (c16 & 7)) + (h & 7)];
      o[j] = f2b(cvs[r] * b2f(raw));
    }
    *(u16x8_t*)(VT + ((size_t)(b * 64 + h)) * SEQ + kt * 128 + 8 * c16) = o;
  }
}

// ---------------- Kernel 4: attention (k-split 8, 4 blocks/CU) ------------
// 256 thr (4 waves), 64 q/wave (2 q-blocks) -> 256 q/block. K+V staged in
// LDS via glld16 (dbuf 2 x (K 4096|V 4096) hw = 32KB). k swept in 64-tiles.
// grid = 8b x 16qt x NS ks; f16 partials when F16P.
template <bool F16P>
__global__ __launch_bounds__(256) void attn_kernel(
    const unsigned short* __restrict__ Qb, const unsigned short* __restrict__ Kb,
    const unsigned short* __restrict__ VT, void* __restrict__ outp, int nkt) {
  __shared__ unsigned short KV[2][8192];  // [buf][K 4096 | V 4096] halfwords
  const int t = threadIdx.x, lane = t & 63, w = t >> 6;
  const int c = lane & 31, hi = lane >> 5;
  const int fid = blockIdx.x;
  const int b = fid & 7, rem = fid >> 3;
  const int qt = rem & 15, ks = rem >> 4;
  const size_t brow = (size_t)b * SEQ;
  const int q0 = qt * 256;
  const int ntiles = 2 * nkt;            // 64-wide tiles per split
  const int t0 = ks * ntiles;            // first tile index

  bf16x8 Qf[2][4];  // persistent B-frags: n = own q row (2 q-blocks of 32)
#pragma unroll
  for (int j = 0; j < 2; ++j)
#pragma unroll
    for (int es = 0; es < 4; ++es)
      Qf[j][es] = ldg8(Qb + (brow + q0 + 64 * w + 32 * j + c) * 64 + 16 * es + 8 * hi);

  f32x16 acc[2][2];
#pragma unroll
  for (int j = 0; j < 2; ++j)
#pragma unroll
    for (int hb = 0; hb < 2; ++hb)
#pragma unroll
      for (int i = 0; i < 16; ++i) acc[j][hb][i] = 0.f;

  auto STAGE = [&](int tt, int bb) {
    const int k0 = (t0 + tt) * 64;
    const size_t kb0 = brow + k0;
#pragma unroll
    for (int i = 0; i < 4; ++i) {
      int rr = w + 4 * i;  // uniform per wave; rr<8: K, else V
      if (rr < 8) {
        int ci = rr * 64 + lane;
        int r = ci >> 3, cL = ci & 7;
        glld16(Kb + (kb0 + r) * 64 + (cL ^ (r & 7)) * 8, (void*)&KV[bb][rr * 512]);
      } else {
        int ci = (rr - 8) * 64 + lane;
        int h = ci >> 3, cL = ci & 7;
        glld16(VT + ((size_t)(b * 64 + h)) * SEQ + k0 + (cL ^ (h & 7)) * 8,
               (void*)&KV[bb][4096 + (rr - 8) * 512]);
      }
    }
  };

  auto COMPUTE = [&](int bb) {
    const unsigned short* Ks = &KV[bb][0];
    const unsigned short* Vs = &KV[bb][4096];
#pragma unroll
    for (int kb = 0; kb < 2; ++kb) {
      bf16x8 KA[4];
#pragma unroll
      for (int es = 0; es < 4; ++es)
        KA[es] = ldsA(&Ks[sidx(32 * kb + c, 16 * es + 8 * hi)]);
      bf16x8 fA[2][2];
#pragma unroll
      for (int j = 0; j < 2; ++j) {
        // QK^T swapped: D[k-row][q-col], col = own q
        f32x16 sv;
#pragma unroll
        for (int i = 0; i < 16; ++i) sv[i] = 0.f;
#pragma unroll
        for (int es = 0; es < 4; ++es) sv = mfma32(KA[es], Qf[j][es], sv);
        float p[16];
#pragma unroll
        for (int i = 0; i < 16; ++i) p[i] = expf2(sv[i]);
        unsigned X0 = cvtpk(p[0], p[1]),  X1 = cvtpk(p[2], p[3]);
        unsigned Y0 = cvtpk(p[4], p[5]),  Y1 = cvtpk(p[6], p[7]);
        plane32swap(X0, Y0); plane32swap(X1, Y1);
        u32x4_t F0 = {X0, X1, Y0, Y1};
        unsigned Z0 = cvtpk(p[8], p[9]),   Z1 = cvtpk(p[10], p[11]);
        unsigned W0 = cvtpk(p[12], p[13]), W1 = cvtpk(p[14], p[15]);
        plane32swap(Z0, W0); plane32swap(Z1, W1);
        u32x4_t F1 = {Z0, Z1, W0, W1};
        fA[j][0] = __builtin_bit_cast(bf16x8, F0);
        fA[j][1] = __builtin_bit_cast(bf16x8, F1);
      }
      // PV: acc[j][q][h] += P_j * V'; V-frags shared across j
#pragma unroll
      for (int hb = 0; hb < 2; ++hb) {
        int h = 32 * hb + c;
        int col0 = 32 * kb + 8 * hi;
        bf16x8 VB0 = ldsA(&Vs[h * 64 + (col0 ^ ((h & 7) << 3))]);
        bf16x8 VB1 = ldsA(&Vs[h * 64 + ((col0 + 16) ^ ((h & 7) << 3))]);
        acc[0][hb] = mfma32(fA[0][0], VB0, acc[0][hb]);
        acc[0][hb] = mfma32(fA[0][1], VB1, acc[0][hb]);
        acc[1][hb] = mfma32(fA[1][0], VB0, acc[1][hb]);
        acc[1][hb] = mfma32(fA[1][1], VB1, acc[1][hb]);
      }
    }
  };

  STAGE(0, 0);
  __syncthreads();
  for (int tt = 0; tt < ntiles; ++tt) {
    if (tt + 1 < ntiles) STAGE(tt + 1, (tt + 1) & 1);
    COMPUTE(tt & 1);
    __syncthreads();
  }
#pragma unroll
  for (int j = 0; j < 2; ++j)
#pragma unroll
    for (int hb = 0; hb < 2; ++hb)
#pragma unroll
      for (int r = 0; r < 16; ++r) {
        int qrow = (r & 3) + 8 * (r >> 2) + 4 * hi;
        size_t idx = (brow + q0 + 64 * w + 32 * j + qrow) * 64 + 32 * hb + c;
        if (F16P) {
          unsigned short* op = (unsigned short*)outp + (size_t)ks * NROW * 64;
          op[idx] = f2h(acc[j][hb][r]);
        } else {
          ((float*)outp)[idx] = acc[j][hb][r];
        }
      }
}

// ---------------- Kernel 5: combine 8 f16 k-split partials ----------------
__global__ __launch_bounds__(256) void osum_kernel(
    const unsigned short* __restrict__ P, float* __restrict__ O) {
  const size_t PS = (size_t)NROW * 64;
  size_t i = ((size_t)blockIdx.x * 256 + threadIdx.x) * 8;
  float o[8] = {0.f, 0.f, 0.f, 0.f, 0.f, 0.f, 0.f, 0.f};
#pragma unroll
  for (int p = 0; p < 8; ++p) {
    u16x8_t v = *(const u16x8_t*)(P + p * PS + i);
#pragma unroll
    for (int j = 0; j < 8; ++j) o[j] += h2f(v[j]);
  }
  float4 o0 = {o[0], o[1], o[2], o[3]}, o1 = {o[4], o[5], o[6], o[7]};
  *(float4*)(O + i) = o0;
  *(float4*)(O + i + 4) = o1;
}

extern "C" void kernel_launch(void* const* d_in, const int* in_sizes, int n_in,
                              void* d_out, int out_size, void* d_ws, size_t ws_size,
                              hipStream_t stream) {
  const float* X  = (const float*)d_in[0];
  const float* Wq = (const float*)d_in[1];
  const float* Wk = (const float*)d_in[2];
  // d_in[3] (Wv) unused: reference computes v with q_net.
  float* Out = (float*)d_out;

  unsigned char* wsb = (unsigned char*)d_ws;
  const size_t QB_OFF = 0;                    // 4 MB bf16
  const size_t KB_OFF = 4194304;              // 4 MB bf16
  const size_t WB_OFF = 8388608;              // 192 KB bf16
  const size_t VT_OFF = 8585216;              // 4 MB bf16
  const size_t OP_OFF = 12779520;             // 32 MB f16 (8 partials)
  // Zpart (1 MB f32) aliases the head of the partial region: it is dead
  // after vtrans consumes it, before attn writes partials (stream-ordered).
  const size_t Z_OFF  = OP_OFF;
  const size_t TOTAL_SPLIT = OP_OFF + (size_t)8 * NROW * 64 * 2;  // 46,333,952

  unsigned short* Qb = (unsigned short*)(wsb + QB_OFF);
  unsigned short* Kb = (unsigned short*)(wsb + KB_OFF);
  unsigned short* Wb = (unsigned short*)(wsb + WB_OFF);
  unsigned short* VT = (unsigned short*)(wsb + VT_OFF);
  float* Zpart       = (float*)(wsb + Z_OFF);
  unsigned short* OpH = (unsigned short*)(wsb + OP_OFF);

  const bool split = (ws_size >= TOTAL_SPLIT);

  hipLaunchKernelGGL(wcvt_kernel, dim3(48), dim3(256), 0, stream, Wq, Wk, Wb);
  hipLaunchKernelGGL(proj_kernel, dim3(NROW / 64), dim3(256), 0, stream, X, Wb, Qb, Kb);
  hipLaunchKernelGGL(colsum_kernel, dim3(1024), dim3(256), 0, stream, Qb, Kb, Zpart);
  hipLaunchKernelGGL(vtrans_kernel, dim3(32, 8), dim3(256), 0, stream, Qb, Zpart, VT);
  if (split) {
    hipLaunchKernelGGL(attn_kernel<true>, dim3(1024), dim3(256), 0, stream,
                       Qb, Kb, VT, (void*)OpH, 4);
    hipLaunchKernelGGL(osum_kernel, dim3(1024), dim3(256), 0, stream, OpH, Out);
  } else {
    hipLaunchKernelGGL(attn_kernel<false>, dim3(128), dim3(256), 0, stream,
                       Qb, Kb, VT, (void*)Out, 32);
  }
}

// Round 11
// 101.232 us; speedup vs baseline: 1.6662x; 1.0454x over previous
//
#include <hip/hip_runtime.h>
#include <hip/hip_bf16.h>
#include <cstdint>

// AttentionHead: B=8, S=4096, E=768, H=64. fp32 in/out.
// Reference quirks: v = x@Wq.T (source bug), softmax over QUERY axis,
// scale = 1/sqrt(S) = 1/64.
//
// out[q,h] = sum_k exp(s[q,k]) * v[k,h] / Z[k],  Z[k] = sum_q exp(s[q,k])
// Qb = bf16(q * 0.125*log2e), Kb = bf16(k * 0.125)  =>  dot(Qb,Kb) = log2e*s
// P = exp2(dot) = e^s. VT[h,k] = cv[k]*Qb[k,h], cv = CSCALE/Z[k].
// |s| <= ~1 -> no max subtraction needed.
//
// R11 = R9 config (k-split 4, colsum q-split 4, 4 f16 partials, REPS=1 —
// best known ~88us) + two VALU reductions targeting the measured 53%
// VALUBusy: (1) STAGE global addresses hoisted to persistent pointers
// advanced by constant stride; (2) MFMA C zero-init hoisted to a single
// loop-invariant f32x16. Bit-identical math, no sync changes.

#define BATCH 8
#define SEQ   4096
#define EMB   768
#define HD    64
#define NROW  (BATCH*SEQ)  // 32768

#define QSCALE 0.1803368801111201f   // 0.125 * log2(e)
#define KSCALE 0.125f
#define CSCALE 5.545177444479562f    // 1 / QSCALE

typedef float  f32x4  __attribute__((ext_vector_type(4)));
typedef float  f32x16 __attribute__((ext_vector_type(16)));
typedef __bf16 bf16x8 __attribute__((ext_vector_type(8)));
typedef unsigned short u16x8_t __attribute__((ext_vector_type(8)));
typedef unsigned int   u32x4_t __attribute__((ext_vector_type(4)));

__device__ __forceinline__ f32x4 mfma16(bf16x8 a, bf16x8 b, f32x4 c) {
  return __builtin_amdgcn_mfma_f32_16x16x32_bf16(a, b, c, 0, 0, 0);
}
__device__ __forceinline__ f32x16 mfma32(bf16x8 a, bf16x8 b, f32x16 c) {
  return __builtin_amdgcn_mfma_f32_32x32x16_bf16(a, b, c, 0, 0, 0);
}
__device__ __forceinline__ unsigned short f2b(float f) {
  __bf16 h = (__bf16)f;
  return __builtin_bit_cast(unsigned short, h);
}
__device__ __forceinline__ float b2f(unsigned short u) {
  unsigned int x = ((unsigned int)u) << 16;
  return __builtin_bit_cast(float, x);
}
__device__ __forceinline__ unsigned short f2h(float f) {
  _Float16 h = (_Float16)f;
  return __builtin_bit_cast(unsigned short, h);
}
__device__ __forceinline__ float h2f(unsigned short u) {
  return (float)__builtin_bit_cast(_Float16, u);
}
__device__ __forceinline__ bf16x8 ldsA(const unsigned short* p) {
  return __builtin_bit_cast(bf16x8, *(const u16x8_t*)p);
}
__device__ __forceinline__ bf16x8 ldg8(const unsigned short* p) {
  return __builtin_bit_cast(bf16x8, *(const u16x8_t*)p);
}
__device__ __forceinline__ float expf2(float x) {  // 2^x
  float r; asm("v_exp_f32 %0, %1" : "=v"(r) : "v"(x)); return r;
}
__device__ __forceinline__ unsigned cvtpk(float lo, float hi) {  // 2 f32 -> 2 bf16
  unsigned r; asm("v_cvt_pk_bf16_f32 %0, %1, %2" : "=v"(r) : "v"(lo), "v"(hi)); return r;
}
__device__ __forceinline__ void plane32swap(unsigned &a, unsigned &b) {
  asm volatile("v_permlane32_swap_b32 %0, %1" : "+v"(a), "+v"(b));
}
__device__ __forceinline__ void glld16(const void* g, void* l) {
  __builtin_amdgcn_global_load_lds(
      (const __attribute__((address_space(1))) void*)g,
      (__attribute__((address_space(3))) void*)l, 16, 0, 0);
}
// G4 XOR swizzle for row-major [R][64] bf16 tiles (halfword index)
__device__ __forceinline__ int sidx(int r, int h) {
  return r * 64 + (h ^ ((r & 7) << 3));
}

// ---------------- Kernel 0: W -> bf16 (Wq rows 0-63 | Wk rows 64-127) ----
__global__ __launch_bounds__(256) void wcvt_kernel(
    const float* __restrict__ Wq, const float* __restrict__ Wk,
    unsigned short* __restrict__ Wb) {
  int ci = blockIdx.x * 256 + threadIdx.x;  // 12288 chunks of 8
  int r = ci / 96, c8 = ci % 96;
  const float* src = (r < 64 ? Wq + (size_t)r * EMB : Wk + (size_t)(r - 64) * EMB) + c8 * 8;
  float4 a = *(const float4*)src, d = *(const float4*)(src + 4);
  u16x8_t o;
  o[0]=f2b(a.x); o[1]=f2b(a.y); o[2]=f2b(a.z); o[3]=f2b(a.w);
  o[4]=f2b(d.x); o[5]=f2b(d.y); o[6]=f2b(d.z); o[7]=f2b(d.w);
  *(u16x8_t*)(Wb + (size_t)ci * 8) = o;
}

// ---------------- Kernel 1: projection GEMM (+X register prefetch, T14) --
__global__ __launch_bounds__(256) void proj_kernel(
    const float* __restrict__ X, const unsigned short* __restrict__ Wb,
    unsigned short* __restrict__ Qb, unsigned short* __restrict__ Kb) {
  __shared__ unsigned short Ws[2][8192];
  const int t = threadIdx.x, lane = t & 63, w = t >> 6;
  const int c = lane & 15, g = lane >> 4;
  const int row0 = blockIdx.x * 64;
  f32x4 acc[8];
#pragma unroll
  for (int f = 0; f < 8; ++f) { acc[f][0]=0.f; acc[f][1]=0.f; acc[f][2]=0.f; acc[f][3]=0.f; }

  auto STAGE = [&](int ec, int bb) {
#pragma unroll
    for (int i = 0; i < 4; ++i) {
      int rr = w + 4 * i;               // uniform per wave
      int ci = rr * 64 + lane;
      int r = ci >> 3, cL = ci & 7;
      glld16(Wb + (size_t)r * EMB + ec * 64 + (cL ^ (r & 7)) * 8, (void*)&Ws[bb][rr * 512]);
    }
  };
  const float* xrow = X + (size_t)(row0 + 16 * w + c) * EMB + 8 * g;
  float4 Xa[4], Xb[4];
  auto LOADX = [&](float4* R, int ec) {
    const float* xp = xrow + ec * 64;
    R[0] = *(const float4*)xp;        R[1] = *(const float4*)(xp + 4);
    R[2] = *(const float4*)(xp + 32); R[3] = *(const float4*)(xp + 36);
  };
  auto COMPUTE = [&](const float4* R, const unsigned short* Wt) {
    bf16x8 Af[2];
#pragma unroll
    for (int es = 0; es < 2; ++es) {
      float4 v0 = R[2 * es], v1 = R[2 * es + 1];
      u16x8_t tmp;
      tmp[0]=f2b(v0.x); tmp[1]=f2b(v0.y); tmp[2]=f2b(v0.z); tmp[3]=f2b(v0.w);
      tmp[4]=f2b(v1.x); tmp[5]=f2b(v1.y); tmp[6]=f2b(v1.z); tmp[7]=f2b(v1.w);
      Af[es] = __builtin_bit_cast(bf16x8, tmp);
    }
#pragma unroll
    for (int es = 0; es < 2; ++es)
#pragma unroll
      for (int f = 0; f < 8; ++f) {
        bf16x8 Bf = ldsA(&Wt[sidx(16 * f + c, es * 32 + 8 * g)]);
        acc[f] = mfma16(Af[es], Bf, acc[f]);
      }
  };

  LOADX(Xa, 0);
  STAGE(0, 0);
  __syncthreads();
#pragma unroll 1
  for (int e2 = 0; e2 < 6; ++e2) {
    int ec = 2 * e2;
    if (ec + 1 < 12) { STAGE(ec + 1, (ec + 1) & 1); LOADX(Xb, ec + 1); }
    COMPUTE(Xa, Ws[ec & 1]);
    __syncthreads();
    if (ec + 2 < 12) { STAGE(ec + 2, (ec + 2) & 1); LOADX(Xa, ec + 2); }
    COMPUTE(Xb, Ws[(ec + 1) & 1]);
    __syncthreads();
  }
#pragma unroll
  for (int f = 0; f < 8; ++f) {
    int n = 16 * f + c;
    float sc = (n < 64) ? QSCALE : KSCALE;
#pragma unroll
    for (int r = 0; r < 4; ++r) {
      int ROW = row0 + 16 * w + 4 * g + r;
      unsigned short bv = f2b(acc[f][r] * sc);
      if (n < 64) Qb[(size_t)ROW * 64 + n] = bv;
      else        Kb[(size_t)ROW * 64 + (n - 64)] = bv;
    }
  }
}

// ---------------- Kernel 2: column exp2-sums (q-split 4, ptr-hoisted) -----
__global__ __launch_bounds__(256) void colsum_kernel(
    const unsigned short* __restrict__ Qb, const unsigned short* __restrict__ Kb,
    float* __restrict__ Zpart) {
  __shared__ unsigned short Qs[2][8192];
  const int t = threadIdx.x, lane = t & 63, w = t >> 6;
  const int c = lane & 31, hi = lane >> 5;
  const int fid = blockIdx.x;
  const int b = fid & 7, rem = fid >> 3;
  const int kt = rem & 15, qs = rem >> 4;
  const size_t kbase = (size_t)b * SEQ + kt * 256;
  const size_t qbase0 = (size_t)b * SEQ + qs * 1024;

  bf16x8 Kf[2][4];  // own 64 k-rows: kbase + 64w + 32j + c
#pragma unroll
  for (int j = 0; j < 2; ++j)
#pragma unroll
    for (int es = 0; es < 4; ++es)
      Kf[j][es] = __builtin_bit_cast(bf16x8,
          *(const u16x8_t*)(Kb + (kbase + 64 * w + 32 * j + c) * 64 + 16 * es + 8 * hi));

  // persistent staging pointers: addr(qi) = base + qi*8192 elements
  const unsigned short* pq[4];
#pragma unroll
  for (int i = 0; i < 4; ++i) {
    int rr = w + 4 * i;
    int ci = rr * 64 + lane;
    int r = ci >> 3, cL = ci & 7;
    pq[i] = Qb + (qbase0 + r) * 64 + (cL ^ (r & 7)) * 8;
  }
  auto STAGE = [&](int bb) {  // issues next stage, advances pointers
#pragma unroll
    for (int i = 0; i < 4; ++i) {
      glld16(pq[i], (void*)&Qs[bb][(w + 4 * i) * 512]);
      pq[i] += 8192;
    }
  };
  f32x16 fz16;
#pragma unroll
  for (int i = 0; i < 16; ++i) fz16[i] = 0.f;

  float csum[2] = {0.f, 0.f};
  STAGE(0);
  __syncthreads();
  for (int qi = 0; qi < 8; ++qi) {
    if (qi < 7) STAGE((qi + 1) & 1);
    const unsigned short* Qt = Qs[qi & 1];
#pragma unroll
    for (int sq = 0; sq < 4; ++sq) {
      bf16x8 A[4];
#pragma unroll
      for (int es = 0; es < 4; ++es)
        A[es] = ldsA(&Qt[sidx(32 * sq + c, 16 * es + 8 * hi)]);
#pragma unroll
      for (int j = 0; j < 2; ++j) {
        f32x16 sv = mfma32(A[0], Kf[j][0], fz16);
#pragma unroll
        for (int es = 1; es < 4; ++es) sv = mfma32(A[es], Kf[j][es], sv);
#pragma unroll
        for (int i = 0; i < 16; ++i) csum[j] += expf2(sv[i]);
      }
    }
    __syncthreads();
  }
#pragma unroll
  for (int j = 0; j < 2; ++j) {
    float v = csum[j] + __shfl_xor(csum[j], 32);  // merge hi row-halves
    if (lane < 32)
      Zpart[(kbase + 64 * w + 32 * j + lane) * 4 + qs] = v;
  }
}

// ---------------- Kernel 3: VT[b][h][k] = cv[k]*Qb[k][h] ------------------
__global__ __launch_bounds__(256) void vtrans_kernel(
    const unsigned short* __restrict__ Qb, const float* __restrict__ Zpart,
    unsigned short* __restrict__ VT) {
  __shared__ unsigned short T[128 * 72];
  __shared__ float cvs[128];
  const int t = threadIdx.x;
  const int kt = blockIdx.x, b = blockIdx.y;
  const size_t kbase = (size_t)b * SEQ + kt * 128;
#pragma unroll
  for (int it = 0; it < 4; ++it) {  // stage 128x64 tile, chunk-swizzled by r>>3
    int ci = t + 256 * it;
    int r = ci >> 3, ch = ci & 7;
    u16x8_t v = *(const u16x8_t*)(Qb + (kbase + r) * 64 + 8 * ch);
    *(u16x8_t*)(&T[r * 72 + 8 * (ch ^ ((r >> 3) & 7))]) = v;
  }
  if (t < 128) {
    const float* zp = Zpart + (kbase + t) * 4;
    cvs[t] = CSCALE / (zp[0] + zp[1] + zp[2] + zp[3]);
  }
  __syncthreads();
#pragma unroll
  for (int it = 0; it < 4; ++it) {
    int ci = t + 256 * it;
    int h = ci >> 4, c16 = ci & 15;
    u16x8_t o;
#pragma unroll
    for (int j = 0; j < 8; ++j) {
      int r = 8 * c16 + j;
      unsigned short raw = T[r * 72 + 8 * ((h >> 3) ^ (c16 & 7)) + (h & 7)];
      o[j] = f2b(cvs[r] * b2f(raw));
    }
    *(u16x8_t*)(VT + ((size_t)(b * 64 + h)) * SEQ + kt * 128 + 8 * c16) = o;
  }
}

// ---------------- Kernel 4: attention (k-split 4, ptr-hoisted STAGE) ------
// 256 thr (4 waves), 64 q/wave (2 q-blocks) -> 256 q/block. K+V staged in
// LDS via glld16 (dbuf 2 x (K 4096|V 4096) hw = 32KB). k swept in 64-tiles.
template <bool F16P>
__global__ __launch_bounds__(256) void attn_kernel(
    const unsigned short* __restrict__ Qb, const unsigned short* __restrict__ Kb,
    const unsigned short* __restrict__ VT, void* __restrict__ outp, int nkt) {
  __shared__ unsigned short KV[2][8192];  // [buf][K 4096 | V 4096] halfwords
  const int t = threadIdx.x, lane = t & 63, w = t >> 6;
  const int c = lane & 31, hi = lane >> 5;
  const int fid = blockIdx.x;
  const int b = fid & 7, rem = fid >> 3;
  const int qt = rem & 15, ks = rem >> 4;
  const size_t brow = (size_t)b * SEQ;
  const int q0 = qt * 256;
  const int ntiles = 2 * nkt;            // 64-wide tiles per split
  const int t0 = ks * ntiles;            // first tile index

  bf16x8 Qf[2][4];  // persistent B-frags: n = own q row (2 q-blocks of 32)
#pragma unroll
  for (int j = 0; j < 2; ++j)
#pragma unroll
    for (int es = 0; es < 4; ++es)
      Qf[j][es] = ldg8(Qb + (brow + q0 + 64 * w + 32 * j + c) * 64 + 16 * es + 8 * hi);

  f32x16 fz16;
#pragma unroll
  for (int i = 0; i < 16; ++i) fz16[i] = 0.f;

  f32x16 acc[2][2];
#pragma unroll
  for (int j = 0; j < 2; ++j)
#pragma unroll
    for (int hb = 0; hb < 2; ++hb)
#pragma unroll
      for (int i = 0; i < 16; ++i) acc[j][hb][i] = 0.f;

  // persistent staging pointers: K advances 4096 el/tile, V 64 el/tile
  const unsigned short *pk0, *pk1, *pv0, *pv1;
  {
    int ci0 = w * 64 + lane, ci1 = (w + 4) * 64 + lane;
    int r0 = ci0 >> 3, c0 = ci0 & 7, r1 = ci1 >> 3, c1 = ci1 & 7;
    pk0 = Kb + (brow + (size_t)t0 * 64 + r0) * 64 + (c0 ^ (r0 & 7)) * 8;
    pk1 = Kb + (brow + (size_t)t0 * 64 + r1) * 64 + (c1 ^ (r1 & 7)) * 8;
    int h0 = ci0 >> 3, h1 = ci1 >> 3;  // V uses same ci pattern
    pv0 = VT + ((size_t)(b * 64 + h0)) * SEQ + t0 * 64 + (c0 ^ (h0 & 7)) * 8;
    pv1 = VT + ((size_t)(b * 64 + h1)) * SEQ + t0 * 64 + (c1 ^ (h1 & 7)) * 8;
  }
  auto STAGE = [&](int bb) {  // issues next tile's loads, advances pointers
    glld16(pk0, (void*)&KV[bb][w * 512]);
    glld16(pk1, (void*)&KV[bb][(w + 4) * 512]);
    glld16(pv0, (void*)&KV[bb][4096 + w * 512]);
    glld16(pv1, (void*)&KV[bb][4096 + (w + 4) * 512]);
    pk0 += 4096; pk1 += 4096; pv0 += 64; pv1 += 64;
  };

  auto COMPUTE = [&](int bb) {
    const unsigned short* Ks = &KV[bb][0];
    const unsigned short* Vs = &KV[bb][4096];
#pragma unroll
    for (int kb = 0; kb < 2; ++kb) {
      bf16x8 KA[4];
#pragma unroll
      for (int es = 0; es < 4; ++es)
        KA[es] = ldsA(&Ks[sidx(32 * kb + c, 16 * es + 8 * hi)]);
      bf16x8 fA[2][2];
#pragma unroll
      for (int j = 0; j < 2; ++j) {
        // QK^T swapped: D[k-row][q-col], col = own q
        f32x16 sv = mfma32(KA[0], Qf[j][0], fz16);
#pragma unroll
        for (int es = 1; es < 4; ++es) sv = mfma32(KA[es], Qf[j][es], sv);
        float p[16];
#pragma unroll
        for (int i = 0; i < 16; ++i) p[i] = expf2(sv[i]);
        unsigned X0 = cvtpk(p[0], p[1]),  X1 = cvtpk(p[2], p[3]);
        unsigned Y0 = cvtpk(p[4], p[5]),  Y1 = cvtpk(p[6], p[7]);
        plane32swap(X0, Y0); plane32swap(X1, Y1);
        u32x4_t F0 = {X0, X1, Y0, Y1};
        unsigned Z0 = cvtpk(p[8], p[9]),   Z1 = cvtpk(p[10], p[11]);
        unsigned W0 = cvtpk(p[12], p[13]), W1 = cvtpk(p[14], p[15]);
        plane32swap(Z0, W0); plane32swap(Z1, W1);
        u32x4_t F1 = {Z0, Z1, W0, W1};
        fA[j][0] = __builtin_bit_cast(bf16x8, F0);
        fA[j][1] = __builtin_bit_cast(bf16x8, F1);
      }
      // PV: acc[j][q][h] += P_j * V'; V-frags shared across j
#pragma unroll
      for (int hb = 0; hb < 2; ++hb) {
        int h = 32 * hb + c;
        int col0 = 32 * kb + 8 * hi;
        bf16x8 VB0 = ldsA(&Vs[h * 64 + (col0 ^ ((h & 7) << 3))]);
        bf16x8 VB1 = ldsA(&Vs[h * 64 + ((col0 + 16) ^ ((h & 7) << 3))]);
        acc[0][hb] = mfma32(fA[0][0], VB0, acc[0][hb]);
        acc[0][hb] = mfma32(fA[0][1], VB1, acc[0][hb]);
        acc[1][hb] = mfma32(fA[1][0], VB0, acc[1][hb]);
        acc[1][hb] = mfma32(fA[1][1], VB1, acc[1][hb]);
      }
    }
  };

  STAGE(0);
  __syncthreads();
  for (int tt = 0; tt < ntiles; ++tt) {
    if (tt + 1 < ntiles) STAGE((tt + 1) & 1);
    COMPUTE(tt & 1);
    __syncthreads();
  }
#pragma unroll
  for (int j = 0; j < 2; ++j)
#pragma unroll
    for (int hb = 0; hb < 2; ++hb)
#pragma unroll
      for (int r = 0; r < 16; ++r) {
        int qrow = (r & 3) + 8 * (r >> 2) + 4 * hi;
        size_t idx = (brow + q0 + 64 * w + 32 * j + qrow) * 64 + 32 * hb + c;
        if (F16P) {
          unsigned short* op = (unsigned short*)outp + (size_t)ks * NROW * 64;
          op[idx] = f2h(acc[j][hb][r]);
        } else {
          ((float*)outp)[idx] = acc[j][hb][r];
        }
      }
}

// ---------------- Kernel 5: combine 4 f16 k-split partials ----------------
__global__ __launch_bounds__(256) void osum_kernel(
    const unsigned short* __restrict__ P, float* __restrict__ O) {
  const size_t PS = (size_t)NROW * 64;
  size_t i = ((size_t)blockIdx.x * 256 + threadIdx.x) * 8;
  u16x8_t a = *(const u16x8_t*)(P + i);
  u16x8_t b = *(const u16x8_t*)(P + PS + i);
  u16x8_t c = *(const u16x8_t*)(P + 2 * PS + i);
  u16x8_t d = *(const u16x8_t*)(P + 3 * PS + i);
  float o[8];
#pragma unroll
  for (int j = 0; j < 8; ++j)
    o[j] = (h2f(a[j]) + h2f(b[j])) + (h2f(c[j]) + h2f(d[j]));
  float4 o0 = {o[0], o[1], o[2], o[3]}, o1 = {o[4], o[5], o[6], o[7]};
  *(float4*)(O + i) = o0;
  *(float4*)(O + i + 4) = o1;
}

extern "C" void kernel_launch(void* const* d_in, const int* in_sizes, int n_in,
                              void* d_out, int out_size, void* d_ws, size_t ws_size,
                              hipStream_t stream) {
  const float* X  = (const float*)d_in[0];
  const float* Wq = (const float*)d_in[1];
  const float* Wk = (const float*)d_in[2];
  // d_in[3] (Wv) unused: reference computes v with q_net.
  float* Out = (float*)d_out;

  unsigned char* wsb = (unsigned char*)d_ws;
  const size_t QB_OFF = 0;                    // 4 MB bf16
  const size_t KB_OFF = 4194304;              // 4 MB bf16
  const size_t WB_OFF = 8388608;              // 192 KB bf16
  const size_t Z_OFF  = 8585216;              // 512 KB f32
  const size_t VT_OFF = 9240576;              // 4 MB bf16
  const size_t OP_OFF = 13434880;             // 16 MB f16 (4 partials)
  const size_t TOTAL_SPLIT = OP_OFF + (size_t)4 * NROW * 64 * 2;  // 30,212,096

  unsigned short* Qb = (unsigned short*)(wsb + QB_OFF);
  unsigned short* Kb = (unsigned short*)(wsb + KB_OFF);
  unsigned short* Wb = (unsigned short*)(wsb + WB_OFF);
  float* Zpart       = (float*)(wsb + Z_OFF);
  unsigned short* VT = (unsigned short*)(wsb + VT_OFF);
  unsigned short* OpH = (unsigned short*)(wsb + OP_OFF);

  const bool split = (ws_size >= TOTAL_SPLIT);

  hipLaunchKernelGGL(wcvt_kernel, dim3(48), dim3(256), 0, stream, Wq, Wk, Wb);
  hipLaunchKernelGGL(proj_kernel, dim3(NROW / 64), dim3(256), 0, stream, X, Wb, Qb, Kb);
  hipLaunchKernelGGL(colsum_kernel, dim3(512), dim3(256), 0, stream, Qb, Kb, Zpart);
  hipLaunchKernelGGL(vtrans_kernel, dim3(32, 8), dim3(256), 0, stream, Qb, Zpart, VT);
  if (split) {
    hipLaunchKernelGGL(attn_kernel<true>, dim3(512), dim3(256), 0, stream,
                       Qb, Kb, VT, (void*)OpH, 8);
    hipLaunchKernelGGL(osum_kernel, dim3(1024), dim3(256), 0, stream, OpH, Out);
  } else {
    hipLaunchKernelGGL(attn_kernel<false>, dim3(128), dim3(256), 0, stream,
                       Qb, Kb, VT, (void*)Out, 32);
  }
}